// Round 2
// baseline (1068.572 us; speedup 1.0000x reference)
//
#include <hip/hip_runtime.h>
#include <hip/hip_fp16.h>

#define BB 32
#define SS 8192
#define CC 128
#define MM 16
#define NUMK 8
#define NL 4

#define TWO_PI 6.2831853071795864769f

// ---------------- k_prep: transpose cw (all layers) and fc1_w ----------------
__global__ __launch_bounds__(256) void k_prep(const float* __restrict__ cw,
                                              const float* __restrict__ fc1_w,
                                              float* __restrict__ cwT,
                                              float* __restrict__ fc1T) {
    int idx = blockIdx.x * 256 + threadIdx.x;
    if (idx < NL * CC * CC) {
        int l = idx >> 14, rem = idx & 16383, i = rem >> 7, o = rem & 127;
        cwT[(l << 14) + (i << 7) + o] = cw[(l << 14) + (o << 7) + i];
    }
    if (idx < CC * CC) {
        int w = idx >> 7, j = idx & 127;
        fc1T[idx] = fc1_w[(j << 7) + w];  // fc1T[w][j] = fc1_w[j][w]
    }
}

// ---------------- k_fc0: h[b][w][s] = fc0(x, grid) ----------------
__global__ __launch_bounds__(256) void k_fc0(const float* __restrict__ x,
                                             const float* __restrict__ fc0_w,
                                             const float* __restrict__ fc0_b,
                                             __half* __restrict__ h) {
    int idx = blockIdx.x * 256 + threadIdx.x;       // (b*CC + w)*SS + s
    int s = idx & (SS - 1);
    int bw = idx >> 13;
    int w = bw & 127;
    int b = bw >> 7;
    float g = (float)s * (1.0f / (float)(SS - 1));
    float xv = x[(b << 13) + s];
    float v = fmaf(fc0_w[2 * w], xv, fmaf(fc0_w[2 * w + 1], g, fc0_b[w]));
    h[idx] = __float2half(v);
}

// ---------------- k_dft: Xf[b][i][m][2] = DFT_16modes(h[b][i][:]) ----------------
// block = (b, channel-group of 4). 4 waves; wave w owns modes 4w..4w+3 for all 4 rows.
__global__ __launch_bounds__(256) void k_dft(const __half* __restrict__ h,
                                             float* __restrict__ Xf) {
    int b = blockIdx.x >> 5, ig = blockIdx.x & 31;
    int lane = threadIdx.x & 63;
    int wv = __builtin_amdgcn_readfirstlane(threadIdx.x >> 6);
    const __half* hp = h + (((b * CC) + ig * 4) << 13);

    float accr[4][4], acci[4][4];   // [mode j][row r]
    float cr[4], ci[4], pc[4], ps[4];
#pragma unroll
    for (int j = 0; j < 4; j++) {
        int m = wv * 4 + j;
        float th0 = (TWO_PI / (float)SS) * (float)(m * lane);
        float sn, cs;
        sincosf(th0, &sn, &cs);
        cr[j] = cs; ci[j] = -sn;                     // e^{-i m th(lane)}
        float ph = (float)m * (TWO_PI * 64.0f / (float)SS);
        sincosf(ph, &sn, &cs);
        pc[j] = cs; ps[j] = -sn;                     // e^{-i m th(64)} step
#pragma unroll
        for (int r = 0; r < 4; r++) { accr[j][r] = 0.f; acci[j][r] = 0.f; }
    }

    for (int k = 0; k < 128; k++) {
        int s = lane + (k << 6);
        float hv[4];
#pragma unroll
        for (int r = 0; r < 4; r++) hv[r] = __half2float(hp[(r << 13) + s]);
#pragma unroll
        for (int j = 0; j < 4; j++) {
#pragma unroll
            for (int r = 0; r < 4; r++) {
                accr[j][r] = fmaf(hv[r], cr[j], accr[j][r]);
                acci[j][r] = fmaf(hv[r], ci[j], acci[j][r]);
            }
            float nc = cr[j] * pc[j] - ci[j] * ps[j];
            float ns = cr[j] * ps[j] + ci[j] * pc[j];
            cr[j] = nc; ci[j] = ns;
        }
    }

#pragma unroll
    for (int j = 0; j < 4; j++) {
#pragma unroll
        for (int r = 0; r < 4; r++) {
            float vr = accr[j][r], vi = acci[j][r];
#pragma unroll
            for (int off = 32; off > 0; off >>= 1) {
                vr += __shfl_xor(vr, off, 64);
                vi += __shfl_xor(vi, off, 64);
            }
            if (lane == 0) {
                int m = wv * 4 + j, i = ig * 4 + r;
                Xf[(((b * CC + i) * MM + m) << 1) + 0] = vr;
                Xf[(((b * CC + i) * MM + m) << 1) + 1] = vi;
            }
        }
    }
}

// ---------------- k_mix: om[b][m][o][2] = geff[m]*(2/S)*(halfDC)*sum_i Xf*w1 ----------------
__global__ __launch_bounds__(256) void k_mix(const float* __restrict__ Xf,
                                             const float* __restrict__ w1_re,
                                             const float* __restrict__ w1_im,
                                             const float* __restrict__ gamma,
                                             const float* __restrict__ fwhm,
                                             const float* __restrict__ w2,
                                             float* __restrict__ om, int l) {
    __shared__ float geff[MM];
    int t = threadIdx.x;
    if (t < MM) {
        float g = 0.f;
        for (int k = 0; k < NUMK; k++) {
            float fw = fwhm[l * NUMK + k];
            float t1 = gamma[l * NUMK + k] * 3.14159265358979f / (fw + 1e-5f);
            float u = (float)t * (1.0f / 8230.0f) - fw;   // u[m+4115] - fwhm
            g = fmaf(w2[l * NUMK + k], expf(-t1 * t1 * u * u), g);
        }
        geff[t] = g;
    }
    __syncthreads();

    int n = blockIdx.x * 256 + t;    // over B*C*M = 65536
    int m = n & 15, o = (n >> 4) & 127, b = n >> 11;
    const float* xf = Xf + ((b * CC) * MM + m) * 2;          // i stride 32
    const float* wr = w1_re + (l << 18) + (o << 4) + m;      // i stride 2048
    const float* wi = w1_im + (l << 18) + (o << 4) + m;
    float orr = 0.f, oii = 0.f;
    for (int i = 0; i < CC; i++) {
        float xr = xf[i * 32], xi = xf[i * 32 + 1];
        float wrv = wr[i * 2048], wiv = wi[i * 2048];
        orr = fmaf(xr, wrv, orr); orr = fmaf(-xi, wiv, orr);
        oii = fmaf(xr, wiv, oii); oii = fmaf(xi, wrv, oii);
    }
    float sc = geff[m] * (2.0f / (float)SS) * ((m == 0) ? 0.5f : 1.0f);
    om[(((b * MM + m) * CC + o) << 1) + 0] = orr * sc;
    om[(((b * MM + m) * CC + o) << 1) + 1] = oii * sc;
}

// ---------------- k_layer: h = gelu?(conv1x1(h) + irfft16(om) + cb), in place ----------------
// block: (b, 64-wide s tile). 4 waves; wave w owns 32 output channels, lane = s.
__global__ __launch_bounds__(256) void k_layer(__half* __restrict__ h,
                                               const float* __restrict__ cwT,
                                               const float* __restrict__ cb,
                                               const float* __restrict__ om,
                                               int l, int do_gelu) {
    __shared__ float tile[CC][64];
    int b = blockIdx.x >> 7;
    int st = (blockIdx.x & 127) << 6;
    int t = threadIdx.x;
    __half* hb = h + ((b * CC) << 13);

#pragma unroll
    for (int r = 0; r < 32; r++) {
        int idx = (r << 8) + t;
        int i = idx >> 6, s = idx & 63;
        tile[i][s] = __half2float(hb[(i << 13) + st + s]);
    }
    __syncthreads();

    int lane = t & 63;
    int wv = __builtin_amdgcn_readfirstlane(t >> 6);
    int o0 = wv << 5;

    float acc[32];
#pragma unroll
    for (int oo = 0; oo < 32; oo++) acc[oo] = cb[l * CC + o0 + oo];

    // irfft: acc += om_r*cos(m th) - om_i*sin(m th)
    int sg = st + lane;
    float th = (TWO_PI / (float)SS) * (float)sg;
    float s1, c1;
    sincosf(th, &s1, &c1);
    float cm = 1.0f, sm = 0.0f;
    for (int m = 0; m < MM; m++) {
        const float* op = om + (((b * MM + m) * CC + o0) << 1);
#pragma unroll
        for (int oo = 0; oo < 32; oo++) {
            acc[oo] += op[2 * oo] * cm - op[2 * oo + 1] * sm;
        }
        float nc = cm * c1 - sm * s1;
        sm = cm * s1 + sm * c1;
        cm = nc;
    }

    // 1x1 conv
    for (int i = 0; i < CC; i++) {
        float hv = tile[i][lane];
        const float* cwp = cwT + (l << 14) + (i << 7) + o0;
#pragma unroll
        for (int oo = 0; oo < 32; oo++) acc[oo] = fmaf(cwp[oo], hv, acc[oo]);
    }

#pragma unroll
    for (int oo = 0; oo < 32; oo++) {
        float v = acc[oo];
        if (do_gelu) v = 0.5f * v * (1.0f + erff(v * 0.70710678118f));
        hb[((o0 + oo) << 13) + st + lane] = __float2half(v);
    }
}

// ---------------- k_head: out = fc2( gelu( fc1(h) ) ) ----------------
__global__ __launch_bounds__(256) void k_head(const __half* __restrict__ h,
                                              const float* __restrict__ fc1T,
                                              const float* __restrict__ fc1_b,
                                              const float* __restrict__ fc2_w,
                                              const float* __restrict__ fc2_b,
                                              float* __restrict__ out) {
    __shared__ float tile[CC][64];
    __shared__ float partial[4][64];
    int b = blockIdx.x >> 7;
    int st = (blockIdx.x & 127) << 6;
    int t = threadIdx.x;
    const __half* hb = h + ((b * CC) << 13);

#pragma unroll
    for (int r = 0; r < 32; r++) {
        int idx = (r << 8) + t;
        int i = idx >> 6, s = idx & 63;
        tile[i][s] = __half2float(hb[(i << 13) + st + s]);
    }
    __syncthreads();

    int lane = t & 63;
    int wv = __builtin_amdgcn_readfirstlane(t >> 6);
    int j0 = wv << 5;

    float acc[32];
#pragma unroll
    for (int jj = 0; jj < 32; jj++) acc[jj] = fc1_b[j0 + jj];

    for (int w = 0; w < CC; w++) {
        float hv = tile[w][lane];
        const float* fp = fc1T + (w << 7) + j0;
#pragma unroll
        for (int jj = 0; jj < 32; jj++) acc[jj] = fmaf(fp[jj], hv, acc[jj]);
    }

    float p = 0.f;
#pragma unroll
    for (int jj = 0; jj < 32; jj++) {
        float v = acc[jj];
        v = 0.5f * v * (1.0f + erff(v * 0.70710678118f));
        p = fmaf(fc2_w[j0 + jj], v, p);
    }
    partial[wv][lane] = p;
    __syncthreads();
    if (t < 64) {
        float r = partial[0][t] + partial[1][t] + partial[2][t] + partial[3][t] + fc2_b[0];
        out[(b << 13) + st + t] = r;
    }
}

extern "C" void kernel_launch(void* const* d_in, const int* in_sizes, int n_in,
                              void* d_out, int out_size, void* d_ws, size_t ws_size,
                              hipStream_t stream) {
    const float* x      = (const float*)d_in[0];
    const float* w1_re  = (const float*)d_in[1];
    const float* w1_im  = (const float*)d_in[2];
    const float* gamma  = (const float*)d_in[3];
    const float* fwhm   = (const float*)d_in[4];
    const float* w2     = (const float*)d_in[5];
    const float* cw     = (const float*)d_in[6];
    const float* cb     = (const float*)d_in[7];
    const float* fc0_w  = (const float*)d_in[8];
    const float* fc0_b  = (const float*)d_in[9];
    const float* fc1_w  = (const float*)d_in[10];
    const float* fc1_b  = (const float*)d_in[11];
    const float* fc2_w  = (const float*)d_in[12];
    const float* fc2_b  = (const float*)d_in[13];
    float* out = (float*)d_out;

    char* ws = (char*)d_ws;
    __half* h   = (__half*)ws;                              // 64 MB
    float* Xf   = (float*)(ws + 67108864);                  // 512 KB
    float* om   = (float*)(ws + 67108864 + 524288);         // 512 KB
    float* cwT  = (float*)(ws + 67108864 + 1048576);        // 256 KB
    float* fc1T = (float*)(ws + 67108864 + 1048576 + 262144); // 64 KB

    k_prep<<<dim3(256), dim3(256), 0, stream>>>(cw, fc1_w, cwT, fc1T);
    k_fc0<<<dim3(131072), dim3(256), 0, stream>>>(x, fc0_w, fc0_b, h);
    for (int l = 0; l < NL; l++) {
        k_dft<<<dim3(1024), dim3(256), 0, stream>>>(h, Xf);
        k_mix<<<dim3(256), dim3(256), 0, stream>>>(Xf, w1_re, w1_im, gamma, fwhm, w2, om, l);
        k_layer<<<dim3(4096), dim3(256), 0, stream>>>(h, cwT, cb, om, l, (l < NL - 1) ? 1 : 0);
    }
    k_head<<<dim3(4096), dim3(256), 0, stream>>>(h, fc1T, fc1_b, fc2_w, fc2_b, out);
}

// Round 4
// 555.384 us; speedup vs baseline: 1.9240x; 1.9240x over previous
//
#include <hip/hip_runtime.h>
#include <hip/hip_fp16.h>

#define BB 32
#define SS 8192
#define CC 128
#define MM 16
#define NUMK 8
#define NL 4

#define TWO_PI 6.2831853071795864769f

typedef _Float16 f16x8 __attribute__((ext_vector_type(8)));
typedef float f32x4 __attribute__((ext_vector_type(4)));

#define MFMA16(a, b, c) __builtin_amdgcn_mfma_f32_16x16x32_f16((a), (b), (c), 0, 0, 0)

__device__ __forceinline__ float gelu_f(float v) {
    return 0.5f * v * (1.0f + erff(v * 0.70710678118f));
}

// ---- module-global scratch (NOT in d_ws): rewritten every call ----
__device__ __align__(256) __half g_trigA[SS * 32];      // 512 KB [s][32]: cos|sin
__device__ __align__(256) __half g_trigD[32 * SS];      // 512 KB [m2][s]: cos rows 0-15, -sin rows 16-31
__device__ __align__(256) __half g_cwh[NL * CC * CC];   // 128 KB [l][o][i]
__device__ __align__(256) __half g_fc1h[CC * CC];       // 32 KB  [j][w]
__device__ __align__(256) __half g_omh[BB * CC * 32];   // 256 KB [b][o][32]: omr*sc | -omi*sc
__device__ __align__(256) float  g_Xfp[BB * 4 * 32 * CC]; // 2 MB [b][sc][m2][i]
__device__ __align__(256) float  g_Xf[BB * 32 * CC];    // 512 KB [b][m2][i]

// ---------------- k_prep: fp16 copies of cw (all layers) and fc1_w ----------------
__global__ __launch_bounds__(256) void k_prep(const float* __restrict__ cw,
                                              const float* __restrict__ fc1_w) {
    int idx = blockIdx.x * 256 + threadIdx.x;
    if (idx < NL * CC * CC) g_cwh[idx] = __float2half(cw[idx]);
    if (idx < CC * CC)      g_fc1h[idx] = __float2half(fc1_w[idx]);
}

// ---------------- k_trig: trig tables ----------------
__global__ __launch_bounds__(256) void k_trig() {
    int s = blockIdx.x * 256 + threadIdx.x;   // 8192
    for (int m = 0; m < MM; m++) {
        int ms = (m * s) & (SS - 1);
        float th = (float)ms * (TWO_PI / (float)SS);
        float sn, cs;
        sincosf(th, &sn, &cs);
        g_trigA[s * 32 + m]        = __float2half(cs);
        g_trigA[s * 32 + 16 + m]   = __float2half(sn);
        g_trigD[m * SS + s]        = __float2half(cs);
        g_trigD[(16 + m) * SS + s] = __float2half(-sn);
    }
}

// ---------------- k_fc0: h[b][s][w] = fc0(x, grid), fp16, channel-fast ----------------
__global__ __launch_bounds__(256) void k_fc0(const float* __restrict__ x,
                                             const float* __restrict__ fc0_w,
                                             const float* __restrict__ fc0_b,
                                             __half2* __restrict__ h2) {
    int idx = blockIdx.x * 256 + threadIdx.x;  // over B*S*64 pairs
    int w2i = idx & 63;
    int s = (idx >> 6) & (SS - 1);
    int b = idx >> 19;
    int w = w2i * 2;
    float g = (float)s * (1.0f / (float)(SS - 1));
    float xv = x[(b << 13) + s];
    float v0 = fmaf(fc0_w[2 * w], xv, fmaf(fc0_w[2 * w + 1], g, fc0_b[w]));
    float v1 = fmaf(fc0_w[2 * w + 2], xv, fmaf(fc0_w[2 * w + 3], g, fc0_b[w + 1]));
    h2[idx] = __floats2half2_rn(v0, v1);
}

// ---------------- k_dft: g_Xfp[b][sc][m2][i] = partial DFT via MFMA ----------------
// block = (b, i-group of 32, s-superchunk of 2048). 4 waves; wave stages 4 chunks of
// 128 s-rows x 32 ch into its private LDS strip (72B row stride), reads transposed.
__global__ __launch_bounds__(256) void k_dft(const __half* __restrict__ h) {
    __shared__ __align__(16) unsigned short sbuf[4][128 * 36];  // 36 KB
    __shared__ float sred[4][1024];                              // 16 KB
    int bi = blockIdx.x;
    int b = bi >> 4, go = (bi >> 2) & 3, sc = bi & 3;
    int t = threadIdx.x;
    int wid = __builtin_amdgcn_readfirstlane(t >> 6);
    int l6 = t & 63, lr = l6 & 15, lg = l6 >> 4;
    const char* h_c = (const char*)h;
    const char* td_c = (const char*)g_trigD;
    unsigned short* st = &sbuf[wid][0];

    f32x4 acc[2][2];
#pragma unroll
    for (int mf = 0; mf < 2; mf++)
#pragma unroll
        for (int nf = 0; nf < 2; nf++) acc[mf][nf] = (f32x4){0.f, 0.f, 0.f, 0.f};

    for (int q = 0; q < 4; q++) {
        int c = wid + ((q >> 1) << 2);
        int s00 = sc * 2048 + c * 256 + (q & 1) * 128;
#pragma unroll
        for (int it = 0; it < 16; it++) {
            int id = (it << 6) + l6;
            int row = id >> 3, part = id & 7;
            unsigned long long v = *(const unsigned long long*)
                (h_c + (((b << 13) + s00 + row) << 8) + (go << 6) + (part << 3));
            *(unsigned long long*)((char*)st + row * 72 + (part << 3)) = v;
        }
        __syncthreads();
#pragma unroll
        for (int ks = 0; ks < 4; ks++) {
            int sbase = s00 + ks * 32 + (lg << 3);
            f16x8 a0 = *(const f16x8*)(td_c + (lr << 14) + (sbase << 1));
            f16x8 a1 = *(const f16x8*)(td_c + ((16 + lr) << 14) + (sbase << 1));
#pragma unroll
            for (int nf = 0; nf < 2; nf++) {
                int il = (nf << 4) + lr;
                int sl0 = ks * 32 + (lg << 3);
                union { unsigned int u[4]; f16x8 v; } bb;
#pragma unroll
                for (int p = 0; p < 4; p++) {
                    unsigned int lo = st[(sl0 + 2 * p) * 36 + il];
                    unsigned int hi = st[(sl0 + 2 * p + 1) * 36 + il];
                    bb.u[p] = lo | (hi << 16);
                }
                acc[0][nf] = MFMA16(a0, bb.v, acc[0][nf]);
                acc[1][nf] = MFMA16(a1, bb.v, acc[1][nf]);
            }
        }
        __syncthreads();
    }
#pragma unroll
    for (int mf = 0; mf < 2; mf++)
#pragma unroll
        for (int nf = 0; nf < 2; nf++)
#pragma unroll
            for (int reg = 0; reg < 4; reg++) {
                int m2 = (mf << 4) + (lg << 2) + reg;
                int il = (nf << 4) + lr;
                sred[wid][m2 * 32 + il] = acc[mf][nf][reg];
            }
    __syncthreads();
#pragma unroll
    for (int q = 0; q < 4; q++) {
        int idx = (q << 8) + t;
        float s = sred[0][idx] + sred[1][idx] + sred[2][idx] + sred[3][idx];
        g_Xfp[(b << 14) + (sc << 12) + ((idx >> 5) << 7) + (go << 5) + (idx & 31)] = s;
    }
}

// ---------------- k_red: g_Xf[b][m2][i] = sum_sc g_Xfp ----------------
__global__ __launch_bounds__(256) void k_red() {
    int t = blockIdx.x * 256 + threadIdx.x;   // 131072
    int b = t >> 12, r = t & 4095;
    float s = 0.f;
#pragma unroll
    for (int sc = 0; sc < 4; sc++) s += g_Xfp[(b << 14) + (sc << 12) + r];
    g_Xf[t] = s;
}

// ---------------- k_mix: g_omh[b][o][k2] fp16: k2<16 -> omr*sc, >=16 -> -omi*sc ------
__global__ __launch_bounds__(256) void k_mix(const float* __restrict__ w1_re,
                                             const float* __restrict__ w1_im,
                                             const float* __restrict__ gamma,
                                             const float* __restrict__ fwhm,
                                             const float* __restrict__ w2, int l) {
    __shared__ float geff[MM];
    int t = threadIdx.x;
    if (t < MM) {
        float g = 0.f;
        for (int k = 0; k < NUMK; k++) {
            float fw = fwhm[l * NUMK + k];
            float t1 = gamma[l * NUMK + k] * 3.14159265358979f / (fw + 1e-5f);
            float u = (float)(t + 1) * (1.0f / 8230.0f) - fw;  // u after ifftshift: (m+1)/8230
            g = fmaf(w2[l * NUMK + k], expf(-t1 * t1 * u * u), g);
        }
        geff[t] = g;
    }
    __syncthreads();

    int n = blockIdx.x * 256 + t;    // over B*C*M = 65536
    int m = n & 15, o = (n >> 4) & 127, b = n >> 11;
    const float* xr = g_Xf + (b << 12) + (m << 7);
    const float* xi = g_Xf + (b << 12) + ((16 + m) << 7);
    const float* wr = w1_re + (l << 18) + (o << 4) + m;
    const float* wi = w1_im + (l << 18) + (o << 4) + m;
    float orr = 0.f, oii = 0.f;
    for (int i = 0; i < CC; i++) {
        float xrv = xr[i], xiv = xi[i];
        float wrv = wr[i << 11], wiv = wi[i << 11];
        orr = fmaf(xrv, wrv, orr); orr = fmaf(-xiv, wiv, orr);
        oii = fmaf(xrv, wiv, oii); oii = fmaf(xiv, wrv, oii);
    }
    float sc = geff[m] * (2.0f / (float)SS) * ((m == 0) ? 0.5f : 1.0f);
    g_omh[(b << 12) + (o << 5) + m]      = __float2half(orr * sc);
    g_omh[(b << 12) + (o << 5) + 16 + m] = __float2half(-oii * sc);
}

// ---------------- k_layer: h[b][s][o] = gelu?(conv + irfft + cb), MFMA, no LDS --------
// block = (b, s-tile 128). wave wid owns s-rows [S0+32wid, +32), all 128 o.
__global__ __launch_bounds__(256) void k_layer(__half* __restrict__ h,
                                               const float* __restrict__ cbl,
                                               int l, int do_gelu) {
    int bi = blockIdx.x;
    int b = bi >> 6, S0 = (bi & 63) << 7;
    int t = threadIdx.x;
    int wid = __builtin_amdgcn_readfirstlane(t >> 6);
    int l6 = t & 63, lr = l6 & 15, lg = l6 >> 4;
    const char* h_c = (const char*)h;
    const char* cw_c = (const char*)(g_cwh + l * CC * CC);
    const char* om_c = (const char*)g_omh;
    const char* ta_c = (const char*)g_trigA;
    int sA0 = S0 + (wid << 5) + lr;

    f32x4 acc[2][8];
#pragma unroll
    for (int mf = 0; mf < 2; mf++)
#pragma unroll
        for (int nf = 0; nf < 8; nf++) acc[mf][nf] = (f32x4){0.f, 0.f, 0.f, 0.f};

#pragma unroll
    for (int ks = 0; ks < 4; ks++) {
        f16x8 a0 = *(const f16x8*)(h_c + (((b << 13) + sA0) << 8) + (ks << 6) + (lg << 4));
        f16x8 a1 = *(const f16x8*)(h_c + (((b << 13) + sA0 + 16) << 8) + (ks << 6) + (lg << 4));
#pragma unroll
        for (int nf = 0; nf < 8; nf++) {
            f16x8 bv = *(const f16x8*)(cw_c + (((nf << 4) + lr) << 8) + (ks << 6) + (lg << 4));
            acc[0][nf] = MFMA16(a0, bv, acc[0][nf]);
            acc[1][nf] = MFMA16(a1, bv, acc[1][nf]);
        }
    }
    {   // irfft K-step: A = [cos|sin](s), B = [omr|-omi](o)
        f16x8 a0 = *(const f16x8*)(ta_c + (sA0 << 6) + (lg << 4));
        f16x8 a1 = *(const f16x8*)(ta_c + ((sA0 + 16) << 6) + (lg << 4));
#pragma unroll
        for (int nf = 0; nf < 8; nf++) {
            f16x8 bv = *(const f16x8*)(om_c + (((b << 7) + (nf << 4) + lr) << 6) + (lg << 4));
            acc[0][nf] = MFMA16(a0, bv, acc[0][nf]);
            acc[1][nf] = MFMA16(a1, bv, acc[1][nf]);
        }
    }
#pragma unroll
    for (int nf = 0; nf < 8; nf++) {
        int o = (nf << 4) + lr;
        float bias = cbl[o];
#pragma unroll
        for (int mf = 0; mf < 2; mf++)
#pragma unroll
            for (int reg = 0; reg < 4; reg++) {
                int s = S0 + (wid << 5) + (mf << 4) + (lg << 2) + reg;
                float v = acc[mf][nf][reg] + bias;
                if (do_gelu) v = gelu_f(v);
                h[(((b << 13) + s) << 7) + o] = __float2half(v);
            }
    }
}

// ---------------- k_head: out = fc2(gelu(fc1(h))), MFMA, no LDS ----------------
__global__ __launch_bounds__(256) void k_head(const __half* __restrict__ h,
                                              const float* __restrict__ fc1_b,
                                              const float* __restrict__ fc2_w,
                                              const float* __restrict__ fc2_b,
                                              float* __restrict__ out) {
    int bi = blockIdx.x;
    int b = bi >> 6, S0 = (bi & 63) << 7;
    int t = threadIdx.x;
    int wid = __builtin_amdgcn_readfirstlane(t >> 6);
    int l6 = t & 63, lr = l6 & 15, lg = l6 >> 4;
    const char* h_c = (const char*)h;
    const char* f1_c = (const char*)g_fc1h;
    int sA0 = S0 + (wid << 5) + lr;

    f32x4 acc[2][8];
#pragma unroll
    for (int mf = 0; mf < 2; mf++)
#pragma unroll
        for (int nf = 0; nf < 8; nf++) acc[mf][nf] = (f32x4){0.f, 0.f, 0.f, 0.f};

#pragma unroll
    for (int ks = 0; ks < 4; ks++) {
        f16x8 a0 = *(const f16x8*)(h_c + (((b << 13) + sA0) << 8) + (ks << 6) + (lg << 4));
        f16x8 a1 = *(const f16x8*)(h_c + (((b << 13) + sA0 + 16) << 8) + (ks << 6) + (lg << 4));
#pragma unroll
        for (int nf = 0; nf < 8; nf++) {
            f16x8 bv = *(const f16x8*)(f1_c + (((nf << 4) + lr) << 8) + (ks << 6) + (lg << 4));
            acc[0][nf] = MFMA16(a0, bv, acc[0][nf]);
            acc[1][nf] = MFMA16(a1, bv, acc[1][nf]);
        }
    }
    float f2b = fc2_b[0];
#pragma unroll
    for (int mf = 0; mf < 2; mf++)
#pragma unroll
        for (int reg = 0; reg < 4; reg++) {
            float p = 0.f;
#pragma unroll
            for (int nf = 0; nf < 8; nf++) {
                int j = (nf << 4) + lr;
                float v = acc[mf][nf][reg] + fc1_b[j];
                v = gelu_f(v);
                p = fmaf(fc2_w[j], v, p);
            }
            p += __shfl_xor(p, 1, 64);
            p += __shfl_xor(p, 2, 64);
            p += __shfl_xor(p, 4, 64);
            p += __shfl_xor(p, 8, 64);
            if (lr == 0) {
                int s = S0 + (wid << 5) + (mf << 4) + (lg << 2) + reg;
                out[(b << 13) + s] = p + f2b;
            }
        }
}

extern "C" void kernel_launch(void* const* d_in, const int* in_sizes, int n_in,
                              void* d_out, int out_size, void* d_ws, size_t ws_size,
                              hipStream_t stream) {
    const float* x      = (const float*)d_in[0];
    const float* w1_re  = (const float*)d_in[1];
    const float* w1_im  = (const float*)d_in[2];
    const float* gamma  = (const float*)d_in[3];
    const float* fwhm   = (const float*)d_in[4];
    const float* w2     = (const float*)d_in[5];
    const float* cw     = (const float*)d_in[6];
    const float* cb     = (const float*)d_in[7];
    const float* fc0_w  = (const float*)d_in[8];
    const float* fc0_b  = (const float*)d_in[9];
    const float* fc1_w  = (const float*)d_in[10];
    const float* fc1_b  = (const float*)d_in[11];
    const float* fc2_w  = (const float*)d_in[12];
    const float* fc2_b  = (const float*)d_in[13];
    float* out = (float*)d_out;

    __half* h = (__half*)d_ws;                      // 64 MiB, [b][s][i] — ONLY ws use

    k_prep<<<dim3(256), dim3(256), 0, stream>>>(cw, fc1_w);
    k_trig<<<dim3(32), dim3(256), 0, stream>>>();
    k_fc0<<<dim3(65536), dim3(256), 0, stream>>>(x, fc0_w, fc0_b, (__half2*)h);
    for (int l = 0; l < NL; l++) {
        k_dft<<<dim3(512), dim3(256), 0, stream>>>(h);
        k_red<<<dim3(512), dim3(256), 0, stream>>>();
        k_mix<<<dim3(256), dim3(256), 0, stream>>>(w1_re, w1_im, gamma, fwhm, w2, l);
        k_layer<<<dim3(2048), dim3(256), 0, stream>>>(h, cb + l * CC, l, (l < NL - 1) ? 1 : 0);
    }
    k_head<<<dim3(2048), dim3(256), 0, stream>>>(h, fc1_b, fc2_w, fc2_b, out);
}

// Round 5
// 478.334 us; speedup vs baseline: 2.2339x; 1.1611x over previous
//
#include <hip/hip_runtime.h>
#include <hip/hip_fp16.h>

#define BB 32
#define SS 8192
#define CC 128
#define MM 16
#define NUMK 8
#define NL 4

#define TWO_PI 6.2831853071795864769f

typedef _Float16 f16x8 __attribute__((ext_vector_type(8)));
typedef float f32x4 __attribute__((ext_vector_type(4)));

#define MFMA16(a, b, c) __builtin_amdgcn_mfma_f32_16x16x32_f16((a), (b), (c), 0, 0, 0)

// tanh-form GELU (max dev from exact erf-GELU ~3e-4, threshold 1.9e-2)
__device__ __forceinline__ float gelu_f(float v) {
    float u = 0.7978845608f * fmaf(0.044715f * v * v, v, v);
    float a = fabsf(u);
    float e = __expf(-2.0f * a);
    float th = __fdividef(1.0f - e, 1.0f + e);
    th = copysignf(th, u);
    return 0.5f * v * (1.0f + th);
}

// ---- module-global scratch (NOT in d_ws): rewritten every call ----
__device__ __align__(256) __half g_trigA[SS * 32];      // [s][32]: cos(ms) k<16 | sin(ms) k>=16
__device__ __align__(256) __half g_trigD[32 * SS];      // [m2][s]: cos rows 0-15, -sin rows 16-31
__device__ __align__(256) __half g_cwh[NL * CC * CC];   // [l][o][i]
__device__ __align__(256) __half g_fc1h[CC * CC];       // [j][w]
__device__ __align__(256) __half g_omh[BB * CC * 32];   // [b][o][32]: omr*sc(+cb at k=0) | -omi*sc
__device__ __align__(256) float  g_Xfp[BB * 4 * 32 * CC]; // [b][sc][m2][i]
__device__ __align__(256) float  g_Xf[BB * 32 * CC];    // [b][m2][i]

// ---------------- k_prep ----------------
__global__ __launch_bounds__(256) void k_prep(const float* __restrict__ cw,
                                              const float* __restrict__ fc1_w) {
    int idx = blockIdx.x * 256 + threadIdx.x;
    if (idx < NL * CC * CC) g_cwh[idx] = __float2half(cw[idx]);
    if (idx < CC * CC)      g_fc1h[idx] = __float2half(fc1_w[idx]);
}

// ---------------- k_trig ----------------
__global__ __launch_bounds__(256) void k_trig() {
    int s = blockIdx.x * 256 + threadIdx.x;   // 8192
    for (int m = 0; m < MM; m++) {
        int ms = (m * s) & (SS - 1);
        float th = (float)ms * (TWO_PI / (float)SS);
        float sn, cs;
        sincosf(th, &sn, &cs);
        g_trigA[s * 32 + m]        = __float2half(cs);
        g_trigA[s * 32 + 16 + m]   = __float2half(sn);
        g_trigD[m * SS + s]        = __float2half(cs);
        g_trigD[(16 + m) * SS + s] = __float2half(-sn);
    }
}

// ---------------- k_fc0: h[b][s][w], fp16 channel-fast ----------------
__global__ __launch_bounds__(256) void k_fc0(const float* __restrict__ x,
                                             const float* __restrict__ fc0_w,
                                             const float* __restrict__ fc0_b,
                                             __half2* __restrict__ h2) {
    int idx = blockIdx.x * 256 + threadIdx.x;  // over B*S*64 pairs
    int w2i = idx & 63;
    int s = (idx >> 6) & (SS - 1);
    int b = idx >> 19;
    int w = w2i * 2;
    float g = (float)s * (1.0f / (float)(SS - 1));
    float xv = x[(b << 13) + s];
    float v0 = fmaf(fc0_w[2 * w], xv, fmaf(fc0_w[2 * w + 1], g, fc0_b[w]));
    float v1 = fmaf(fc0_w[2 * w + 2], xv, fmaf(fc0_w[2 * w + 3], g, fc0_b[w + 1]));
    h2[idx] = __floats2half2_rn(v0, v1);
}

// ---------------- k_dft: g_Xfp[b][sc][m2][i] partial DFT via MFMA ----------------
__global__ __launch_bounds__(256) void k_dft(const __half* __restrict__ h) {
    __shared__ __align__(16) unsigned short sbuf[4][128 * 36];
    __shared__ float sred[4][1024];
    int bi = blockIdx.x;
    int b = bi >> 4, go = (bi >> 2) & 3, sc = bi & 3;
    int t = threadIdx.x;
    int wid = __builtin_amdgcn_readfirstlane(t >> 6);
    int l6 = t & 63, lr = l6 & 15, lg = l6 >> 4;
    const char* h_c = (const char*)h;
    const char* td_c = (const char*)g_trigD;
    unsigned short* st = &sbuf[wid][0];

    f32x4 acc[2][2];
#pragma unroll
    for (int mf = 0; mf < 2; mf++)
#pragma unroll
        for (int nf = 0; nf < 2; nf++) acc[mf][nf] = (f32x4){0.f, 0.f, 0.f, 0.f};

    for (int q = 0; q < 4; q++) {
        int c = wid + ((q >> 1) << 2);
        int s00 = sc * 2048 + c * 256 + (q & 1) * 128;
#pragma unroll
        for (int it = 0; it < 16; it++) {
            int id = (it << 6) + l6;
            int row = id >> 3, part = id & 7;
            unsigned long long v = *(const unsigned long long*)
                (h_c + (((b << 13) + s00 + row) << 8) + (go << 6) + (part << 3));
            *(unsigned long long*)((char*)st + row * 72 + (part << 3)) = v;
        }
        __syncthreads();
#pragma unroll
        for (int ks = 0; ks < 4; ks++) {
            int sbase = s00 + ks * 32 + (lg << 3);
            f16x8 a0 = *(const f16x8*)(td_c + (lr << 14) + (sbase << 1));
            f16x8 a1 = *(const f16x8*)(td_c + ((16 + lr) << 14) + (sbase << 1));
#pragma unroll
            for (int nf = 0; nf < 2; nf++) {
                int il = (nf << 4) + lr;
                int sl0 = ks * 32 + (lg << 3);
                union { unsigned int u[4]; f16x8 v; } bb;
#pragma unroll
                for (int p = 0; p < 4; p++) {
                    unsigned int lo = st[(sl0 + 2 * p) * 36 + il];
                    unsigned int hi = st[(sl0 + 2 * p + 1) * 36 + il];
                    bb.u[p] = lo | (hi << 16);
                }
                acc[0][nf] = MFMA16(a0, bb.v, acc[0][nf]);
                acc[1][nf] = MFMA16(a1, bb.v, acc[1][nf]);
            }
        }
        __syncthreads();
    }
#pragma unroll
    for (int mf = 0; mf < 2; mf++)
#pragma unroll
        for (int nf = 0; nf < 2; nf++)
#pragma unroll
            for (int reg = 0; reg < 4; reg++) {
                int m2 = (mf << 4) + (lg << 2) + reg;
                int il = (nf << 4) + lr;
                sred[wid][m2 * 32 + il] = acc[mf][nf][reg];
            }
    __syncthreads();
#pragma unroll
    for (int q = 0; q < 4; q++) {
        int idx = (q << 8) + t;
        float s = sred[0][idx] + sred[1][idx] + sred[2][idx] + sred[3][idx];
        g_Xfp[(b << 14) + (sc << 12) + ((idx >> 5) << 7) + (go << 5) + (idx & 31)] = s;
    }
}

// ---------------- k_red ----------------
__global__ __launch_bounds__(256) void k_red() {
    int t = blockIdx.x * 256 + threadIdx.x;   // 131072
    int b = t >> 12, r = t & 4095;
    float s = 0.f;
#pragma unroll
    for (int sc = 0; sc < 4; sc++) s += g_Xfp[(b << 14) + (sc << 12) + r];
    g_Xf[t] = s;
}

// ---------------- k_mix: g_omh, bias folded into k=0 slot ----------------
__global__ __launch_bounds__(256) void k_mix(const float* __restrict__ w1_re,
                                             const float* __restrict__ w1_im,
                                             const float* __restrict__ gamma,
                                             const float* __restrict__ fwhm,
                                             const float* __restrict__ w2,
                                             const float* __restrict__ cb, int l) {
    __shared__ float geff[MM];
    int t = threadIdx.x;
    if (t < MM) {
        float g = 0.f;
        for (int k = 0; k < NUMK; k++) {
            float fw = fwhm[l * NUMK + k];
            float t1 = gamma[l * NUMK + k] * 3.14159265358979f / (fw + 1e-5f);
            float u = (float)t * (1.0f / 8230.0f) - fw;   // u[4115+m] = m/8230
            g = fmaf(w2[l * NUMK + k], expf(-t1 * t1 * u * u), g);
        }
        geff[t] = g;
    }
    __syncthreads();

    int n = blockIdx.x * 256 + t;    // over B*C*M = 65536
    int m = n & 15, o = (n >> 4) & 127, b = n >> 11;
    const float* xr = g_Xf + (b << 12) + (m << 7);
    const float* xi = g_Xf + (b << 12) + ((16 + m) << 7);
    const float* wr = w1_re + (l << 18) + (o << 4) + m;
    const float* wi = w1_im + (l << 18) + (o << 4) + m;
    float orr = 0.f, oii = 0.f;
    for (int i = 0; i < CC; i++) {
        float xrv = xr[i], xiv = xi[i];
        float wrv = wr[i << 11], wiv = wi[i << 11];
        orr = fmaf(xrv, wrv, orr); orr = fmaf(-xiv, wiv, orr);
        oii = fmaf(xrv, wiv, oii); oii = fmaf(xiv, wrv, oii);
    }
    float sc = geff[m] * (2.0f / (float)SS) * ((m == 0) ? 0.5f : 1.0f);
    float base = (m == 0) ? cb[l * CC + o] : 0.0f;   // bias rides the cos(0)=1 column
    g_omh[(b << 12) + (o << 5) + m]      = __float2half(orr * sc + base);
    g_omh[(b << 12) + (o << 5) + 16 + m] = __float2half(-oii * sc);
}

// ---------------- k_layer: swapped operands; A=cw/om (o rows), B=h/trig (s cols) ------
// wave owns 32 s-cols (2 B-frags) x 128 o (8 A-frags). D: lane holds 4 consecutive o.
__global__ __launch_bounds__(256) void k_layer(__half* __restrict__ h, int l, int do_gelu) {
    int bi = blockIdx.x;
    int b = bi >> 6, S0 = (bi & 63) << 7;
    int t = threadIdx.x;
    int wid = __builtin_amdgcn_readfirstlane(t >> 6);
    int l6 = t & 63, lr = l6 & 15, lg = l6 >> 4;
    const char* h_c = (const char*)h;
    char* hw = (char*)h;
    const char* cw_c = (const char*)(g_cwh + l * CC * CC);
    const char* om_c = (const char*)g_omh;
    const char* ta_c = (const char*)g_trigA;
    int sB0 = S0 + (wid << 5);
    int hrow0 = (((b << 13) + sB0 + lr) << 8);

    f32x4 acc[8][2];
#pragma unroll
    for (int af = 0; af < 8; af++)
#pragma unroll
        for (int bf = 0; bf < 2; bf++) acc[af][bf] = (f32x4){0.f, 0.f, 0.f, 0.f};

#pragma unroll
    for (int ks = 0; ks < 4; ks++) {
        f16x8 b0 = *(const f16x8*)(h_c + hrow0 + (ks << 6) + (lg << 4));
        f16x8 b1 = *(const f16x8*)(h_c + hrow0 + (16 << 8) + (ks << 6) + (lg << 4));
#pragma unroll
        for (int af = 0; af < 8; af++) {
            f16x8 av = *(const f16x8*)(cw_c + (((af << 4) + lr) << 8) + (ks << 6) + (lg << 4));
            acc[af][0] = MFMA16(av, b0, acc[af][0]);
            acc[af][1] = MFMA16(av, b1, acc[af][1]);
        }
    }
    {   // irfft K-step (+bias via k=0): A=omh rows o, B=trigA cols s
        f16x8 t0 = *(const f16x8*)(ta_c + ((sB0 + lr) << 6) + (lg << 4));
        f16x8 t1 = *(const f16x8*)(ta_c + ((sB0 + 16 + lr) << 6) + (lg << 4));
#pragma unroll
        for (int af = 0; af < 8; af++) {
            f16x8 av = *(const f16x8*)(om_c + (((b << 7) + (af << 4) + lr) << 6) + (lg << 4));
            acc[af][0] = MFMA16(av, t0, acc[af][0]);
            acc[af][1] = MFMA16(av, t1, acc[af][1]);
        }
    }
#pragma unroll
    for (int af = 0; af < 8; af++)
#pragma unroll
        for (int bf = 0; bf < 2; bf++) {
            int s = sB0 + (bf << 4) + lr;
            int o0 = (af << 4) + (lg << 2);
            float v0 = acc[af][bf][0], v1 = acc[af][bf][1];
            float v2 = acc[af][bf][2], v3 = acc[af][bf][3];
            if (do_gelu) { v0 = gelu_f(v0); v1 = gelu_f(v1); v2 = gelu_f(v2); v3 = gelu_f(v3); }
            union { __half2 q[2]; unsigned long long u; } pk;
            pk.q[0] = __floats2half2_rn(v0, v1);
            pk.q[1] = __floats2half2_rn(v2, v3);
            *(unsigned long long*)(hw + (((b << 13) + s) << 8) + (o0 << 1)) = pk.u;
        }
}

// ---------------- k_head: swapped; A=fc1 (j rows), B=h (s cols) ----------------
__global__ __launch_bounds__(256) void k_head(const __half* __restrict__ h,
                                              const float* __restrict__ fc1_b,
                                              const float* __restrict__ fc2_w,
                                              const float* __restrict__ fc2_b,
                                              float* __restrict__ out) {
    int bi = blockIdx.x;
    int b = bi >> 6, S0 = (bi & 63) << 7;
    int t = threadIdx.x;
    int wid = __builtin_amdgcn_readfirstlane(t >> 6);
    int l6 = t & 63, lr = l6 & 15, lg = l6 >> 4;
    const char* h_c = (const char*)h;
    const char* f1_c = (const char*)g_fc1h;
    int sB0 = S0 + (wid << 5);
    int hrow0 = (((b << 13) + sB0 + lr) << 8);

    f32x4 acc[8][2];
#pragma unroll
    for (int af = 0; af < 8; af++)
#pragma unroll
        for (int bf = 0; bf < 2; bf++) acc[af][bf] = (f32x4){0.f, 0.f, 0.f, 0.f};

#pragma unroll
    for (int ks = 0; ks < 4; ks++) {
        f16x8 b0 = *(const f16x8*)(h_c + hrow0 + (ks << 6) + (lg << 4));
        f16x8 b1 = *(const f16x8*)(h_c + hrow0 + (16 << 8) + (ks << 6) + (lg << 4));
#pragma unroll
        for (int af = 0; af < 8; af++) {
            f16x8 av = *(const f16x8*)(f1_c + (((af << 4) + lr) << 8) + (ks << 6) + (lg << 4));
            acc[af][0] = MFMA16(av, b0, acc[af][0]);
            acc[af][1] = MFMA16(av, b1, acc[af][1]);
        }
    }
    float f2b = fc2_b[0];
    float p[2] = {0.f, 0.f};
#pragma unroll
    for (int af = 0; af < 8; af++) {
        float4 fb = *(const float4*)(fc1_b + (af << 4) + (lg << 2));
        float4 f2 = *(const float4*)(fc2_w + (af << 4) + (lg << 2));
#pragma unroll
        for (int bf = 0; bf < 2; bf++) {
            float v0 = gelu_f(acc[af][bf][0] + fb.x);
            float v1 = gelu_f(acc[af][bf][1] + fb.y);
            float v2 = gelu_f(acc[af][bf][2] + fb.z);
            float v3 = gelu_f(acc[af][bf][3] + fb.w);
            p[bf] += f2.x * v0 + f2.y * v1 + f2.z * v2 + f2.w * v3;
        }
    }
#pragma unroll
    for (int bf = 0; bf < 2; bf++) {
        float v = p[bf];
        v += __shfl_xor(v, 16, 64);
        v += __shfl_xor(v, 32, 64);
        if (lg == 0) out[(b << 13) + sB0 + (bf << 4) + lr] = v + f2b;
    }
}

extern "C" void kernel_launch(void* const* d_in, const int* in_sizes, int n_in,
                              void* d_out, int out_size, void* d_ws, size_t ws_size,
                              hipStream_t stream) {
    const float* x      = (const float*)d_in[0];
    const float* w1_re  = (const float*)d_in[1];
    const float* w1_im  = (const float*)d_in[2];
    const float* gamma  = (const float*)d_in[3];
    const float* fwhm   = (const float*)d_in[4];
    const float* w2     = (const float*)d_in[5];
    const float* cw     = (const float*)d_in[6];
    const float* cb     = (const float*)d_in[7];
    const float* fc0_w  = (const float*)d_in[8];
    const float* fc0_b  = (const float*)d_in[9];
    const float* fc1_w  = (const float*)d_in[10];
    const float* fc1_b  = (const float*)d_in[11];
    const float* fc2_w  = (const float*)d_in[12];
    const float* fc2_b  = (const float*)d_in[13];
    float* out = (float*)d_out;

    __half* h = (__half*)d_ws;                      // 64 MiB, [b][s][i]

    k_prep<<<dim3(256), dim3(256), 0, stream>>>(cw, fc1_w);
    k_trig<<<dim3(32), dim3(256), 0, stream>>>();
    k_fc0<<<dim3(65536), dim3(256), 0, stream>>>(x, fc0_w, fc0_b, (__half2*)h);
    for (int l = 0; l < NL; l++) {
        k_dft<<<dim3(512), dim3(256), 0, stream>>>(h);
        k_red<<<dim3(512), dim3(256), 0, stream>>>();
        k_mix<<<dim3(256), dim3(256), 0, stream>>>(w1_re, w1_im, gamma, fwhm, w2, cb, l);
        k_layer<<<dim3(2048), dim3(256), 0, stream>>>(h, l, (l < NL - 1) ? 1 : 0);
    }
    k_head<<<dim3(2048), dim3(256), 0, stream>>>(h, fc1_b, fc2_w, fc2_b, out);
}

// Round 6
// 423.543 us; speedup vs baseline: 2.5229x; 1.1294x over previous
//
#include <hip/hip_runtime.h>
#include <hip/hip_fp16.h>

#define BB 32
#define SS 8192
#define CC 128
#define MM 16
#define NUMK 8
#define NL 4

#define TWO_PI 6.2831853071795864769f

typedef _Float16 f16x8 __attribute__((ext_vector_type(8)));
typedef float f32x4 __attribute__((ext_vector_type(4)));

#define MFMA16(a, b, c) __builtin_amdgcn_mfma_f32_16x16x32_f16((a), (b), (c), 0, 0, 0)

// tanh-form GELU (max dev from exact erf-GELU ~3e-4, threshold 1.9e-2)
__device__ __forceinline__ float gelu_f(float v) {
    float u = 0.7978845608f * fmaf(0.044715f * v * v, v, v);
    float a = fabsf(u);
    float e = __expf(-2.0f * a);
    float th = __fdividef(1.0f - e, 1.0f + e);
    th = copysignf(th, u);
    return 0.5f * v * (1.0f + th);
}

// ---- module-global scratch (NOT in d_ws): fully rewritten every call ----
__device__ __align__(256) __half g_trigA[SS * 32];      // [s][32]: cos(ms) k<16 | sin(ms) k>=16
__device__ __align__(256) __half g_trigD[32 * SS];      // [m2][s]: cos rows 0-15, -sin rows 16-31
__device__ __align__(256) __half g_cwh[NL * CC * CC];   // [l][o][i]
__device__ __align__(256) __half g_fc1h[CC * CC];       // [j][w]
__device__ __align__(256) __half g_omh[BB * CC * 32];   // [b][o][32]: omr*sc(+cb at k=0) | -omi*sc
__device__ __align__(256) float  g_Xfp[BB * 64 * 32 * CC]; // 32 MB [b][t64][m2][i] DFT partials
__device__ __align__(256) float  g_Xf[BB * 32 * CC];    // [b][m2][i]
__device__ __align__(256) float  g_Xx[BB * MM * 2];     // DFT of x
__device__ __align__(256) float  g_Xg[MM * 2];          // DFT of grid

// ---------------- k_prep ----------------
__global__ __launch_bounds__(256) void k_prep(const float* __restrict__ cw,
                                              const float* __restrict__ fc1_w) {
    int idx = blockIdx.x * 256 + threadIdx.x;
    if (idx < NL * CC * CC) g_cwh[idx] = __float2half(cw[idx]);
    if (idx < CC * CC)      g_fc1h[idx] = __float2half(fc1_w[idx]);
}

// ---------------- k_trig ----------------
__global__ __launch_bounds__(256) void k_trig() {
    int s = blockIdx.x * 256 + threadIdx.x;   // 8192
    for (int m = 0; m < MM; m++) {
        int ms = (m * s) & (SS - 1);
        float th = (float)ms * (TWO_PI / (float)SS);
        float sn, cs;
        sincosf(th, &sn, &cs);
        g_trigA[s * 32 + m]        = __float2half(cs);
        g_trigA[s * 32 + 16 + m]   = __float2half(sn);
        g_trigD[m * SS + s]        = __float2half(cs);
        g_trigD[(16 + m) * SS + s] = __float2half(-sn);
    }
}

// ---------------- k_dftx: Xx[b][m] (blocks 0-31), Xg[m] (block 32) ----------------
__global__ __launch_bounds__(256) void k_dftx(const float* __restrict__ x) {
    __shared__ float red[4][MM][2];
    int blk = blockIdx.x;
    int t = threadIdx.x;
    int lane = t & 63;
    int wv = t >> 6;

    float accR[MM], accI[MM], cr[MM], ci[MM], pc[MM], ps[MM];
#pragma unroll
    for (int m = 0; m < MM; m++) {
        float sn, cs;
        sincosf((TWO_PI / (float)SS) * (float)(m * t), &sn, &cs);
        cr[m] = cs; ci[m] = -sn;
        sincosf((TWO_PI * 256.0f / (float)SS) * (float)m, &sn, &cs);
        pc[m] = cs; ps[m] = -sn;
        accR[m] = 0.f; accI[m] = 0.f;
    }
    for (int k = 0; k < 32; k++) {
        int s = t + (k << 8);
        float v = (blk < BB) ? x[(blk << 13) + s] : (float)s * (1.0f / 8191.0f);
#pragma unroll
        for (int m = 0; m < MM; m++) {
            accR[m] = fmaf(v, cr[m], accR[m]);
            accI[m] = fmaf(v, ci[m], accI[m]);
            float nc = cr[m] * pc[m] - ci[m] * ps[m];
            float ns = cr[m] * ps[m] + ci[m] * pc[m];
            cr[m] = nc; ci[m] = ns;
        }
    }
#pragma unroll
    for (int m = 0; m < MM; m++) {
#pragma unroll
        for (int off = 32; off > 0; off >>= 1) {
            accR[m] += __shfl_xor(accR[m], off, 64);
            accI[m] += __shfl_xor(accI[m], off, 64);
        }
        if (lane == 0) { red[wv][m][0] = accR[m]; red[wv][m][1] = accI[m]; }
    }
    __syncthreads();
    if (t < MM * 2) {
        int m = t >> 1, p = t & 1;
        float s = red[0][m][p] + red[1][m][p] + red[2][m][p] + red[3][m][p];
        if (blk < BB) g_Xx[(blk << 5) + (m << 1) + p] = s;
        else          g_Xg[(m << 1) + p] = s;
    }
}

// ---------------- k_xf0: analytic layer-0 Xf from fc0 affinity ----------------
__global__ __launch_bounds__(256) void k_xf0(const float* __restrict__ fc0_w,
                                             const float* __restrict__ fc0_b) {
    int n = blockIdx.x * 256 + threadIdx.x;   // B*32*128 = 131072
    int i = n & 127, m2 = (n >> 7) & 31, b = n >> 12;
    int m = m2 & 15, p = m2 >> 4;             // p=0 re, p=1 im
    float xv = g_Xx[(b << 5) + (m << 1) + p];
    float gv = g_Xg[(m << 1) + p];
    float v = fc0_w[2 * i] * xv + fc0_w[2 * i + 1] * gv;
    if (p == 0 && m == 0) v += (float)SS * fc0_b[i];
    g_Xf[(b << 12) + (m2 << 7) + i] = v;
}

// ---------------- k_fc0: h[b][s][w], fp16 channel-fast ----------------
__global__ __launch_bounds__(256) void k_fc0(const float* __restrict__ x,
                                             const float* __restrict__ fc0_w,
                                             const float* __restrict__ fc0_b,
                                             __half2* __restrict__ h2) {
    int idx = blockIdx.x * 256 + threadIdx.x;  // over B*S*64 pairs
    int w2i = idx & 63;
    int s = (idx >> 6) & (SS - 1);
    int b = idx >> 19;
    int w = w2i * 2;
    float g = (float)s * (1.0f / (float)(SS - 1));
    float xv = x[(b << 13) + s];
    float v0 = fmaf(fc0_w[2 * w], xv, fmaf(fc0_w[2 * w + 1], g, fc0_b[w]));
    float v1 = fmaf(fc0_w[2 * w + 2], xv, fmaf(fc0_w[2 * w + 3], g, fc0_b[w + 1]));
    h2[idx] = __floats2half2_rn(v0, v1);
}

// ---------------- k_red2: g_Xf[b][m2][i] = sum_t64 g_Xfp ----------------
__global__ __launch_bounds__(256) void k_red2() {
    int n = blockIdx.x * 256 + threadIdx.x;   // 131072
    int i = n & 127, m2 = (n >> 7) & 31, b = n >> 12;
    const float* p = g_Xfp + (((b << 6) << 5) + (m2 << 7)) + i;
    float s = 0.f;
#pragma unroll 8
    for (int t = 0; t < 64; t++) s += p[t << 12];
    g_Xf[(b << 12) + (m2 << 7) + i] = s;
}

// ---------------- k_mix: g_omh, bias folded into k=0 slot ----------------
__global__ __launch_bounds__(256) void k_mix(const float* __restrict__ w1_re,
                                             const float* __restrict__ w1_im,
                                             const float* __restrict__ gamma,
                                             const float* __restrict__ fwhm,
                                             const float* __restrict__ w2,
                                             const float* __restrict__ cb, int l) {
    __shared__ float geff[MM];
    int t = threadIdx.x;
    if (t < MM) {
        float g = 0.f;
        for (int k = 0; k < NUMK; k++) {
            float fw = fwhm[l * NUMK + k];
            float t1 = gamma[l * NUMK + k] * 3.14159265358979f / (fw + 1e-5f);
            float u = (float)t * (1.0f / 8230.0f) - fw;   // u[4115+m] = m/8230
            g = fmaf(w2[l * NUMK + k], expf(-t1 * t1 * u * u), g);
        }
        geff[t] = g;
    }
    __syncthreads();

    int n = blockIdx.x * 256 + t;    // over B*C*M = 65536
    int m = n & 15, o = (n >> 4) & 127, b = n >> 11;
    const float* xr = g_Xf + (b << 12) + (m << 7);
    const float* xi = g_Xf + (b << 12) + ((16 + m) << 7);
    const float* wr = w1_re + (l << 18) + (o << 4) + m;
    const float* wi = w1_im + (l << 18) + (o << 4) + m;
    float orr = 0.f, oii = 0.f;
    for (int i = 0; i < CC; i++) {
        float xrv = xr[i], xiv = xi[i];
        float wrv = wr[i << 11], wiv = wi[i << 11];
        orr = fmaf(xrv, wrv, orr); orr = fmaf(-xiv, wiv, orr);
        oii = fmaf(xrv, wiv, oii); oii = fmaf(xiv, wrv, oii);
    }
    float sc = geff[m] * (2.0f / (float)SS) * ((m == 0) ? 0.5f : 1.0f);
    float base = (m == 0) ? cb[l * CC + o] : 0.0f;   // bias rides the cos(0)=1 column
    g_omh[(b << 12) + (o << 5) + m]      = __float2half(orr * sc + base);
    g_omh[(b << 12) + (o << 5) + 16 + m] = __float2half(-oii * sc);
}

// ---------------- k_layer: GEMM+irfft(+GELU +fused-DFT-partials) ----------------
// TAIL=1 (l<3): gelu + stash tile in LDS + DFT-partial MFMA -> g_Xfp[b][t64]
template <int TAIL>
__global__ __launch_bounds__(256) void k_layer(__half* __restrict__ h, int l) {
    __shared__ char ldst[TAIL ? 32768 : 16];
    int bi = blockIdx.x;
    int b = bi >> 6, t64 = bi & 63, S0 = t64 << 7;
    int t = threadIdx.x;
    int wid = __builtin_amdgcn_readfirstlane(t >> 6);
    int l6 = t & 63, lr = l6 & 15, lg = l6 >> 4;
    const char* h_c = (const char*)h;
    char* hw = (char*)h;
    const char* cw_c = (const char*)(g_cwh + l * CC * CC);
    const char* om_c = (const char*)g_omh;
    const char* ta_c = (const char*)g_trigA;
    int sB0 = S0 + (wid << 5);
    int hrow0 = (((b << 13) + sB0 + lr) << 8);

    f32x4 acc[8][2];
#pragma unroll
    for (int af = 0; af < 8; af++)
#pragma unroll
        for (int bf = 0; bf < 2; bf++) acc[af][bf] = (f32x4){0.f, 0.f, 0.f, 0.f};

#pragma unroll
    for (int ks = 0; ks < 4; ks++) {
        f16x8 b0 = *(const f16x8*)(h_c + hrow0 + (ks << 6) + (lg << 4));
        f16x8 b1 = *(const f16x8*)(h_c + hrow0 + (16 << 8) + (ks << 6) + (lg << 4));
#pragma unroll
        for (int af = 0; af < 8; af++) {
            f16x8 av = *(const f16x8*)(cw_c + (((af << 4) + lr) << 8) + (ks << 6) + (lg << 4));
            acc[af][0] = MFMA16(av, b0, acc[af][0]);
            acc[af][1] = MFMA16(av, b1, acc[af][1]);
        }
    }
    {   // irfft K-step (+bias via k=0): A=omh rows o, B=trigA cols s
        f16x8 t0 = *(const f16x8*)(ta_c + ((sB0 + lr) << 6) + (lg << 4));
        f16x8 t1 = *(const f16x8*)(ta_c + ((sB0 + 16 + lr) << 6) + (lg << 4));
#pragma unroll
        for (int af = 0; af < 8; af++) {
            f16x8 av = *(const f16x8*)(om_c + (((b << 7) + (af << 4) + lr) << 6) + (lg << 4));
            acc[af][0] = MFMA16(av, t0, acc[af][0]);
            acc[af][1] = MFMA16(av, t1, acc[af][1]);
        }
    }
#pragma unroll
    for (int af = 0; af < 8; af++)
#pragma unroll
        for (int bf = 0; bf < 2; bf++) {
            int s_loc = (wid << 5) + (bf << 4) + lr;
            int s = S0 + s_loc;
            int o0 = (af << 4) + (lg << 2);
            float v0 = acc[af][bf][0], v1 = acc[af][bf][1];
            float v2 = acc[af][bf][2], v3 = acc[af][bf][3];
            if (TAIL) { v0 = gelu_f(v0); v1 = gelu_f(v1); v2 = gelu_f(v2); v3 = gelu_f(v3); }
            union { __half2 q[2]; unsigned long long u; } pk;
            pk.q[0] = __floats2half2_rn(v0, v1);
            pk.q[1] = __floats2half2_rn(v2, v3);
            *(unsigned long long*)(hw + (((b << 13) + s) << 8) + (o0 << 1)) = pk.u;
            if (TAIL) {  // stash tile: [s_loc][o] 2B, swizzled within 256B row
                int byte = (s_loc << 8) + ((o0 << 1) ^ ((s_loc & 15) << 4));
                *(unsigned long long*)(ldst + byte) = pk.u;
            }
        }
    if (TAIL) {
        __syncthreads();
        // DFT partials: A = trigD (m2 rows, global s), B = LDS tile transposed read.
        const char* td_c = (const char*)g_trigD;
        int o0r = wid << 5;
        f32x4 dacc[2][2];
#pragma unroll
        for (int mf = 0; mf < 2; mf++)
#pragma unroll
            for (int nf = 0; nf < 2; nf++) dacc[mf][nf] = (f32x4){0.f, 0.f, 0.f, 0.f};
#pragma unroll
        for (int ks = 0; ks < 4; ks++) {
            int sg = S0 + (ks << 5) + (lg << 3);
            f16x8 a0 = *(const f16x8*)(td_c + ((lr << 13) + sg) * 2);
            f16x8 a1 = *(const f16x8*)(td_c + (((16 + lr) << 13) + sg) * 2);
#pragma unroll
            for (int nf = 0; nf < 2; nf++) {
                int o = o0r + (nf << 4) + lr;
                int sl0 = (ks << 5) + (lg << 3);
                union { unsigned int u[4]; f16x8 v; } bb;
#pragma unroll
                for (int p = 0; p < 4; p++) {
                    int s0 = sl0 + 2 * p, s1 = sl0 + 2 * p + 1;
                    unsigned int lo = *(const unsigned short*)
                        (ldst + (s0 << 8) + ((o << 1) ^ ((s0 & 15) << 4)));
                    unsigned int hi = *(const unsigned short*)
                        (ldst + (s1 << 8) + ((o << 1) ^ ((s1 & 15) << 4)));
                    bb.u[p] = lo | (hi << 16);
                }
                dacc[0][nf] = MFMA16(a0, bb.v, dacc[0][nf]);
                dacc[1][nf] = MFMA16(a1, bb.v, dacc[1][nf]);
            }
        }
        float* xp = g_Xfp + (((b << 6) + t64) << 12);
#pragma unroll
        for (int mf = 0; mf < 2; mf++)
#pragma unroll
            for (int nf = 0; nf < 2; nf++)
#pragma unroll
                for (int reg = 0; reg < 4; reg++) {
                    int m2 = (mf << 4) + (lg << 2) + reg;
                    int o = o0r + (nf << 4) + lr;
                    xp[(m2 << 7) + o] = dacc[mf][nf][reg];
                }
    }
}

// ---------------- k_head: A=fc1 (j rows), B=h (s cols) ----------------
__global__ __launch_bounds__(256) void k_head(const __half* __restrict__ h,
                                              const float* __restrict__ fc1_b,
                                              const float* __restrict__ fc2_w,
                                              const float* __restrict__ fc2_b,
                                              float* __restrict__ out) {
    int bi = blockIdx.x;
    int b = bi >> 6, S0 = (bi & 63) << 7;
    int t = threadIdx.x;
    int wid = __builtin_amdgcn_readfirstlane(t >> 6);
    int l6 = t & 63, lr = l6 & 15, lg = l6 >> 4;
    const char* h_c = (const char*)h;
    const char* f1_c = (const char*)g_fc1h;
    int sB0 = S0 + (wid << 5);
    int hrow0 = (((b << 13) + sB0 + lr) << 8);

    f32x4 acc[8][2];
#pragma unroll
    for (int af = 0; af < 8; af++)
#pragma unroll
        for (int bf = 0; bf < 2; bf++) acc[af][bf] = (f32x4){0.f, 0.f, 0.f, 0.f};

#pragma unroll
    for (int ks = 0; ks < 4; ks++) {
        f16x8 b0 = *(const f16x8*)(h_c + hrow0 + (ks << 6) + (lg << 4));
        f16x8 b1 = *(const f16x8*)(h_c + hrow0 + (16 << 8) + (ks << 6) + (lg << 4));
#pragma unroll
        for (int af = 0; af < 8; af++) {
            f16x8 av = *(const f16x8*)(f1_c + (((af << 4) + lr) << 8) + (ks << 6) + (lg << 4));
            acc[af][0] = MFMA16(av, b0, acc[af][0]);
            acc[af][1] = MFMA16(av, b1, acc[af][1]);
        }
    }
    float f2b = fc2_b[0];
    float p[2] = {0.f, 0.f};
#pragma unroll
    for (int af = 0; af < 8; af++) {
        float4 fb = *(const float4*)(fc1_b + (af << 4) + (lg << 2));
        float4 f2 = *(const float4*)(fc2_w + (af << 4) + (lg << 2));
#pragma unroll
        for (int bf = 0; bf < 2; bf++) {
            float v0 = gelu_f(acc[af][bf][0] + fb.x);
            float v1 = gelu_f(acc[af][bf][1] + fb.y);
            float v2 = gelu_f(acc[af][bf][2] + fb.z);
            float v3 = gelu_f(acc[af][bf][3] + fb.w);
            p[bf] += f2.x * v0 + f2.y * v1 + f2.z * v2 + f2.w * v3;
        }
    }
#pragma unroll
    for (int bf = 0; bf < 2; bf++) {
        float v = p[bf];
        v += __shfl_xor(v, 16, 64);
        v += __shfl_xor(v, 32, 64);
        if (lg == 0) out[(b << 13) + sB0 + (bf << 4) + lr] = v + f2b;
    }
}

extern "C" void kernel_launch(void* const* d_in, const int* in_sizes, int n_in,
                              void* d_out, int out_size, void* d_ws, size_t ws_size,
                              hipStream_t stream) {
    const float* x      = (const float*)d_in[0];
    const float* w1_re  = (const float*)d_in[1];
    const float* w1_im  = (const float*)d_in[2];
    const float* gamma  = (const float*)d_in[3];
    const float* fwhm   = (const float*)d_in[4];
    const float* w2     = (const float*)d_in[5];
    const float* cw     = (const float*)d_in[6];
    const float* cb     = (const float*)d_in[7];
    const float* fc0_w  = (const float*)d_in[8];
    const float* fc0_b  = (const float*)d_in[9];
    const float* fc1_w  = (const float*)d_in[10];
    const float* fc1_b  = (const float*)d_in[11];
    const float* fc2_w  = (const float*)d_in[12];
    const float* fc2_b  = (const float*)d_in[13];
    float* out = (float*)d_out;

    __half* h = (__half*)d_ws;                      // 64 MiB, [b][s][i]

    k_prep<<<dim3(256), dim3(256), 0, stream>>>(cw, fc1_w);
    k_trig<<<dim3(32), dim3(256), 0, stream>>>();
    k_dftx<<<dim3(33), dim3(256), 0, stream>>>(x);
    k_xf0<<<dim3(512), dim3(256), 0, stream>>>(fc0_w, fc0_b);
    k_fc0<<<dim3(65536), dim3(256), 0, stream>>>(x, fc0_w, fc0_b, (__half2*)h);
    for (int l = 0; l < NL; l++) {
        k_mix<<<dim3(256), dim3(256), 0, stream>>>(w1_re, w1_im, gamma, fwhm, w2, cb, l);
        if (l < NL - 1) {
            k_layer<1><<<dim3(2048), dim3(256), 0, stream>>>(h, l);
            k_red2<<<dim3(512), dim3(256), 0, stream>>>();
        } else {
            k_layer<0><<<dim3(2048), dim3(256), 0, stream>>>(h, l);
        }
    }
    k_head<<<dim3(2048), dim3(256), 0, stream>>>(h, fc1_b, fc2_w, fc2_b, out);
}